// Round 10
// baseline (859.406 us; speedup 1.0000x reference)
//
#include <hip/hip_runtime.h>

#define DD     64     // channels
#define WSTR   136    // LDS W^T row stride (bf16): 2-way conflicts only (free)
#define BSH    9      // 512 nodes per bucket
#define BNODES 512
#define BCAPSH 13     // 8192 edges capacity per bucket (mean 6400 + 22 sigma)
#define MAGIC  0x1357ACE5
#define READY_OFF 256 // bar[] index of the init-ready flag

typedef unsigned int uint32;
typedef __attribute__((ext_vector_type(8))) short short8;   // 8 bf16 (4 VGPRs)
typedef __attribute__((ext_vector_type(4))) float f32x4;    // MFMA accumulator

__device__ __forceinline__ unsigned short f2bf_rne(float f) {
    uint32 u = __float_as_uint(f);
    u += 0x7fffu + ((u >> 16) & 1u);
    return (unsigned short)(u >> 16);
}
__device__ __forceinline__ float bf_lo(uint32 w) { return __uint_as_float(w << 16); }
__device__ __forceinline__ float bf_hi(uint32 w) { return __uint_as_float(w & 0xffff0000u); }
__device__ __forceinline__ float bf2f(unsigned short s) {
    return __uint_as_float(((uint32)s) << 16);
}

struct KParams {
    const float* x;
    const int* src;
    const int* dst;
    const float *Wl0, *bl0, *Wr0, *Wl1, *bl1, *Wr1, *Wl2, *bl2, *Wr2;
    const float *g0, *b0, *g1, *b1;
    unsigned short *HB0, *HB1, *AGGB;
    int2* bucketBuf;
    int *csr, *offsets, *gCnt, *bar;
    float* out;
    int N, E, NB, n4, ntiles;
};

struct SmemB { int cnt[256]; int base[256]; };
struct SmemC { int c1[BNODES]; int s[BNODES]; int tmp[256]; };
struct SmemE { unsigned short sWt[64 * WSTR]; float sbl[64]; float sg[64]; float sb[64]; };
union SmemU { SmemB b; SmemC c; SmemE e; };

// Device-wide barrier: per-slot counter (64 B apart). Counters zeroed by the
// init protocol at kernel start (ws is re-poisoned before every launch).
__device__ __forceinline__ void gbar(int* bar, int slot, int nblk) {
    __syncthreads();
    if (threadIdx.x == 0) {
        __threadfence();
        atomicAdd(&bar[slot * 16], 1);
        while (atomicAdd(&bar[slot * 16], 0) < nblk) __builtin_amdgcn_s_sleep(2);
        __threadfence();
    }
    __syncthreads();
}

__global__ __launch_bounds__(256, 4) void mega(KParams p) {
    __shared__ SmemU sm;
    const int t    = threadIdx.x;
    const int bid  = blockIdx.x;
    const int nblk = gridDim.x;

    // ---- init: block 0 zeroes barrier slots + gCnt, then releases everyone
    if (bid == 0) {
        if (t < 16)  p.bar[t * 16] = 0;
        if (t < 256) p.gCnt[t] = 0;
    }
    __syncthreads();
    if (t == 0) {
        if (bid == 0) { __threadfence(); atomicExch(&p.bar[READY_OFF], MAGIC); }
        else {
            while (atomicAdd(&p.bar[READY_OFF], 0) != MAGIC) __builtin_amdgcn_s_sleep(2);
            __threadfence();
        }
    }
    __syncthreads();

    // ================= Phase A: x -> bf16 HB0 =================
    for (int i = bid * 256 + t; i < p.n4; i += nblk * 256) {
        float4 v = ((const float4*)p.x)[i];
        ushort4 q;
        q.x = f2bf_rne(v.x); q.y = f2bf_rne(v.y);
        q.z = f2bf_rne(v.z); q.w = f2bf_rne(v.w);
        ((ushort4*)p.HB0)[i] = q;
    }
    gbar(p.bar, 0, nblk);

    // ================= Phase B: bucket edges by dst>>9 =================
    {
        const int nchunk = (p.E + 4095) >> 12;
        for (int c = bid; c < nchunk; c += nblk) {
            sm.b.cnt[t] = 0;
            __syncthreads();
            const int e0 = c * 4096;
            int sv[16], dv[16], rk[16];
#pragma unroll
            for (int k = 0; k < 4; ++k) {
                int e = e0 + k * 1024 + t * 4;
#pragma unroll
                for (int u = 0; u < 4; ++u) dv[k * 4 + u] = -1;
                if (e < p.E) {
                    int4 s4 = *(const int4*)(p.src + e);
                    int4 d4 = *(const int4*)(p.dst + e);
                    sv[k * 4 + 0] = s4.x; sv[k * 4 + 1] = s4.y;
                    sv[k * 4 + 2] = s4.z; sv[k * 4 + 3] = s4.w;
                    dv[k * 4 + 0] = d4.x; dv[k * 4 + 1] = d4.y;
                    dv[k * 4 + 2] = d4.z; dv[k * 4 + 3] = d4.w;
                    rk[k * 4 + 0] = atomicAdd(&sm.b.cnt[d4.x >> BSH], 1);
                    rk[k * 4 + 1] = atomicAdd(&sm.b.cnt[d4.y >> BSH], 1);
                    rk[k * 4 + 2] = atomicAdd(&sm.b.cnt[d4.z >> BSH], 1);
                    rk[k * 4 + 3] = atomicAdd(&sm.b.cnt[d4.w >> BSH], 1);
                }
            }
            __syncthreads();
            if (sm.b.cnt[t] > 0) sm.b.base[t] = atomicAdd(&p.gCnt[t], sm.b.cnt[t]);
            __syncthreads();
#pragma unroll
            for (int k = 0; k < 16; ++k) {
                if (dv[k] >= 0) {
                    int bk = dv[k] >> BSH;
                    int pos = (bk << BCAPSH) + sm.b.base[bk] + rk[k];
                    p.bucketBuf[pos] = make_int2(sv[k], dv[k]);
                }
            }
            __syncthreads();
        }
    }
    gbar(p.bar, 1, nblk);

    // ================= Phase C: per-bucket CSR build =================
    {
        for (int b = bid; b < p.NB; b += nblk) {
            // bucket base = prefix over gCnt[0..b)
            sm.c.tmp[t] = (t < p.NB) ? p.gCnt[t] : 0;
            __syncthreads();
            for (int d = 1; d < 256; d <<= 1) {
                int v = (t >= d) ? sm.c.tmp[t - d] : 0;
                __syncthreads();
                if (t >= d) sm.c.tmp[t] += v;
                __syncthreads();
            }
            const int base = (b == 0) ? 0 : sm.c.tmp[b - 1];
            __syncthreads();

            sm.c.c1[t] = 0; sm.c.c1[t + 256] = 0;
            __syncthreads();
            const int cnt = p.gCnt[b];
            const int2* bb = p.bucketBuf + ((size_t)b << BCAPSH);
            for (int i = t; i < cnt; i += 256)
                atomicAdd(&sm.c.c1[bb[i].y & (BNODES - 1)], 1);
            __syncthreads();

            // exclusive scan of c1[512] via pairs
            int a0 = sm.c.c1[2 * t], a1 = sm.c.c1[2 * t + 1];
            int pp = a0 + a1;
            sm.c.tmp[t] = pp;
            __syncthreads();
            for (int d = 1; d < 256; d <<= 1) {
                int v = (t >= d) ? sm.c.tmp[t - d] : 0;
                __syncthreads();
                if (t >= d) sm.c.tmp[t] += v;
                __syncthreads();
            }
            int ex = sm.c.tmp[t] - pp;
            sm.c.s[2 * t]     = ex;
            sm.c.s[2 * t + 1] = ex + a0;
            int n0g = (b << BSH) + 2 * t;
            if (n0g < p.N)     p.offsets[n0g]     = base + ex;
            if (n0g + 1 < p.N) p.offsets[n0g + 1] = base + ex + a0;
            if (b == 0 && t == 0) p.offsets[p.N] = p.E;
            __syncthreads();
            sm.c.c1[t] = 0; sm.c.c1[t + 256] = 0;
            __syncthreads();
            for (int i = t; i < cnt; i += 256) {
                int2 e = bb[i];
                int d = e.y & (BNODES - 1);
                int r = atomicAdd(&sm.c.c1[d], 1);
                p.csr[base + sm.c.s[d] + r] = e.x;
            }
            __syncthreads();
        }
    }
    gbar(p.bar, 2, nblk);

    // ================= Layers =================
    const unsigned short* HBin = p.HB0;
    unsigned short* HBout = p.HB1;
    int barSlot = 3;

    for (int layer = 0; layer < 3; ++layer) {
        const float *Wl, *bl, *Wr, *gg, *bb2;
        if (layer == 0)      { Wl = p.Wl0; bl = p.bl0; Wr = p.Wr0; gg = p.g0; bb2 = p.b0; }
        else if (layer == 1) { Wl = p.Wl1; bl = p.bl1; Wr = p.Wr1; gg = p.g1; bb2 = p.b1; }
        else                 { Wl = p.Wl2; bl = p.bl2; Wr = p.Wr2; gg = nullptr; bb2 = nullptr; }

        // ---- Phase D: gather neighbor means -> AGGB (bf16)
        {
            const int q = t & 7;
            const int gstep = nblk * 32;
            for (int node = bid * 32 + (t >> 3); node < p.N; node += gstep) {
                const int off0 = p.offsets[node];
                const int off1 = p.offsets[node + 1];
                float a0 = 0.f, a1 = 0.f, a2 = 0.f, a3 = 0.f,
                      a4 = 0.f, a5 = 0.f, a6 = 0.f, a7 = 0.f;
                for (int j = off0; j < off1; j += 8) {
                    uint4 v[8];
#pragma unroll
                    for (int s = 0; s < 8; ++s) {
                        uint4 tt = make_uint4(0u, 0u, 0u, 0u);
                        int idx = j + s;
                        if (idx < off1) {
                            int sn = __builtin_nontemporal_load(&p.csr[idx]);
                            tt = ((const uint4*)(HBin + (size_t)sn * DD))[q];
                        }
                        v[s] = tt;
                    }
#pragma unroll
                    for (int s = 0; s < 8; ++s) {
                        a0 += bf_lo(v[s].x); a1 += bf_hi(v[s].x);
                        a2 += bf_lo(v[s].y); a3 += bf_hi(v[s].y);
                        a4 += bf_lo(v[s].z); a5 += bf_hi(v[s].z);
                        a6 += bf_lo(v[s].w); a7 += bf_hi(v[s].w);
                    }
                }
                float invd = 1.0f / fmaxf((float)(off1 - off0), 1.0f);
                unsigned short* orow = p.AGGB + (size_t)node * DD + q * 8;
                ushort4 pa, pb;
                pa.x = f2bf_rne(a0 * invd); pa.y = f2bf_rne(a1 * invd);
                pa.z = f2bf_rne(a2 * invd); pa.w = f2bf_rne(a3 * invd);
                pb.x = f2bf_rne(a4 * invd); pb.y = f2bf_rne(a5 * invd);
                pb.z = f2bf_rne(a6 * invd); pb.w = f2bf_rne(a7 * invd);
                *(ushort4*)(orow)     = pa;
                *(ushort4*)(orow + 4) = pb;
            }
        }
        gbar(p.bar, barSlot++, nblk);

        // ---- Phase E: MFMA node update
        {
            for (int idx = t; idx < 2 * DD * DD; idx += 256) {
                int k = idx >> 6, c = idx & 63;
                float v = (k < DD) ? Wl[idx] : Wr[idx - DD * DD];
                sm.e.sWt[c * WSTR + k] = f2bf_rne(v);
            }
            if (t < DD) {
                sm.e.sbl[t] = bl[t];
                if (layer < 2) { sm.e.sg[t] = gg[t]; sm.e.sb[t] = bb2[t]; }
            }
            __syncthreads();

            const int wave = t >> 6;
            const int lane = t & 63;
            const int quad = lane >> 4;
            const int n16  = lane & 15;

            for (int tile = bid; tile < p.ntiles; tile += nblk) {
                const int nbase = tile * 64 + wave * 16;
                const int arow  = min(nbase + n16, p.N - 1);
                const unsigned short* mrow = p.AGGB + (size_t)arow * DD;
                const unsigned short* hrow = HBin   + (size_t)arow * DD;
                short8 af0 = *(const short8*)(mrow + quad * 8);
                short8 af1 = *(const short8*)(mrow + 32 + quad * 8);
                short8 af2 = *(const short8*)(hrow + quad * 8);
                short8 af3 = *(const short8*)(hrow + 32 + quad * 8);

                f32x4 acc[4];
#pragma unroll
                for (int j = 0; j < 4; ++j) {
                    float bv = sm.e.sbl[j * 16 + n16];
                    acc[j] = (f32x4){bv, bv, bv, bv};
                }
#pragma unroll
                for (int j = 0; j < 4; ++j) {
                    short8 bf;
                    bf = *(const short8*)(&sm.e.sWt[(j * 16 + n16) * WSTR + 0 * 32 + quad * 8]);
                    acc[j] = __builtin_amdgcn_mfma_f32_16x16x32_bf16(af0, bf, acc[j], 0, 0, 0);
                    bf = *(const short8*)(&sm.e.sWt[(j * 16 + n16) * WSTR + 1 * 32 + quad * 8]);
                    acc[j] = __builtin_amdgcn_mfma_f32_16x16x32_bf16(af1, bf, acc[j], 0, 0, 0);
                    bf = *(const short8*)(&sm.e.sWt[(j * 16 + n16) * WSTR + 2 * 32 + quad * 8]);
                    acc[j] = __builtin_amdgcn_mfma_f32_16x16x32_bf16(af2, bf, acc[j], 0, 0, 0);
                    bf = *(const short8*)(&sm.e.sWt[(j * 16 + n16) * WSTR + 3 * 32 + quad * 8]);
                    acc[j] = __builtin_amdgcn_mfma_f32_16x16x32_bf16(af3, bf, acc[j], 0, 0, 0);
                }

#pragma unroll
                for (int i = 0; i < 4; ++i) {
                    const int rr = nbase + quad * 4 + i;
                    const int rc = min(rr, p.N - 1);
                    float res[4];
#pragma unroll
                    for (int j = 0; j < 4; ++j)
                        res[j] = bf2f(HBin[(size_t)rc * DD + j * 16 + n16]);
                    float o[4];
                    if (layer < 2) {
                        float s4 = acc[0][i] + acc[1][i] + acc[2][i] + acc[3][i];
                        s4 += __shfl_xor(s4, 1, 64);
                        s4 += __shfl_xor(s4, 2, 64);
                        s4 += __shfl_xor(s4, 4, 64);
                        s4 += __shfl_xor(s4, 8, 64);
                        float mu = s4 * (1.0f / 64.0f);
                        float d0 = acc[0][i] - mu, d1 = acc[1][i] - mu,
                              d2 = acc[2][i] - mu, d3 = acc[3][i] - mu;
                        float qq = d0 * d0 + d1 * d1 + d2 * d2 + d3 * d3;
                        qq += __shfl_xor(qq, 1, 64);
                        qq += __shfl_xor(qq, 2, 64);
                        qq += __shfl_xor(qq, 4, 64);
                        qq += __shfl_xor(qq, 8, 64);
                        float rstd = rsqrtf(qq * (1.0f / 64.0f) + 1e-5f);
                        o[0] = fmaxf(d0 * rstd * sm.e.sg[ 0 + n16] + sm.e.sb[ 0 + n16], 0.f) + res[0];
                        o[1] = fmaxf(d1 * rstd * sm.e.sg[16 + n16] + sm.e.sb[16 + n16], 0.f) + res[1];
                        o[2] = fmaxf(d2 * rstd * sm.e.sg[32 + n16] + sm.e.sb[32 + n16], 0.f) + res[2];
                        o[3] = fmaxf(d3 * rstd * sm.e.sg[48 + n16] + sm.e.sb[48 + n16], 0.f) + res[3];
                        if (rr < p.N) {
#pragma unroll
                            for (int j = 0; j < 4; ++j)
                                HBout[(size_t)rr * DD + j * 16 + n16] = f2bf_rne(o[j]);
                        }
                    } else {
                        o[0] = acc[0][i] + res[0];
                        o[1] = acc[1][i] + res[1];
                        o[2] = acc[2][i] + res[2];
                        o[3] = acc[3][i] + res[3];
                        float qq = o[0] * o[0] + o[1] * o[1] + o[2] * o[2] + o[3] * o[3];
                        qq += __shfl_xor(qq, 1, 64);
                        qq += __shfl_xor(qq, 2, 64);
                        qq += __shfl_xor(qq, 4, 64);
                        qq += __shfl_xor(qq, 8, 64);
                        float inv = 1.0f / fmaxf(sqrtf(qq), 1e-12f);
                        if (rr < p.N) {
#pragma unroll
                            for (int j = 0; j < 4; ++j)
                                p.out[(size_t)rr * DD + j * 16 + n16] = o[j] * inv;
                        }
                    }
                }
            }
        }
        if (layer < 2) gbar(p.bar, barSlot++, nblk);

        const unsigned short* tp = HBin;
        HBin  = HBout;
        HBout = (unsigned short*)tp;
    }
}

// ===========================================================================
extern "C" void kernel_launch(void* const* d_in, const int* in_sizes, int n_in,
                              void* d_out, int out_size, void* d_ws, size_t ws_size,
                              hipStream_t stream) {
    KParams kp;
    kp.x   = (const float*)d_in[0];
    const int* ei = (const int*)d_in[1];
    kp.Wl0 = (const float*)d_in[2];  kp.bl0 = (const float*)d_in[3];
    kp.Wr0 = (const float*)d_in[4];
    kp.Wl1 = (const float*)d_in[5];  kp.bl1 = (const float*)d_in[6];
    kp.Wr1 = (const float*)d_in[7];
    kp.Wl2 = (const float*)d_in[8];  kp.bl2 = (const float*)d_in[9];
    kp.Wr2 = (const float*)d_in[10];
    kp.g0  = (const float*)d_in[11]; kp.b0  = (const float*)d_in[12];
    kp.g1  = (const float*)d_in[13]; kp.b1  = (const float*)d_in[14];

    const int N = in_sizes[0] / DD;   // 100000
    const int E = in_sizes[1] / 2;    // 1250000
    kp.N = N; kp.E = E;
    kp.src = ei;
    kp.dst = ei + E;
    kp.NB = (N + BNODES - 1) >> BSH;
    kp.n4 = N * DD / 4;
    kp.ntiles = (N + 63) / 64;
    kp.out = (float*)d_out;

    // Workspace: bucketBuf int2[256<<13] (16 MB) | HB0 | HB1 | AGGB (bf16 N*64)
    //            | csr[E] | offsets[N+1] | gCnt[256] | bar[272]
    kp.bucketBuf = (int2*)d_ws;
    kp.HB0  = (unsigned short*)(kp.bucketBuf + ((size_t)256 << BCAPSH));
    kp.HB1  = kp.HB0 + (size_t)N * DD;
    kp.AGGB = kp.HB1 + (size_t)N * DD;
    kp.csr  = (int*)(kp.AGGB + (size_t)N * DD);
    kp.offsets = kp.csr + E;
    kp.gCnt = kp.offsets + (N + 1);
    kp.bar  = kp.gCnt + 256;

    int occ = 0;
    hipError_t err = hipOccupancyMaxActiveBlocksPerMultiprocessor(&occ, (const void*)mega, 256, 0);
    if (err != hipSuccess || occ < 1) occ = 4;
    if (occ > 8) occ = 8;
    const int nblk = occ * 256;   // 256 CUs on MI355X; grid fully co-resident

    mega<<<nblk, 256, 0, stream>>>(kp);
}